// Round 6
// baseline (204.855 us; speedup 1.0000x reference)
//
#include <hip/hip_runtime.h>
#include <math.h>

// Group-limited MoE router, T=131072 tokens x E=256 experts.
// 8 lanes per token. Round 9 = Round-7 (best bench, 202.0us) structure with
// the two proven-safe trims from Round 8:
//  - direct strided global loads (phase-1 LDS transpose measured neutral)
//  - first-layer chunk-sort CEs drop the statically-false idx tie-break
// Crucially REVERTS Round-8's regressions: writeback is unconditional and
// happens BEFORE rank (overlaps the rank/msk compute; no divergent write),
// grp comes from the ctz chain (no gw LDS round-trip on the critical path),
// and LDS stays 33KB so the compiler doesn't squeeze VGPRs to 32 (R8: VGPR=32,
// serialized, VALUBusy 50%, warm 77->88.6us). All compare/tie rules and the
// exact sigmoid are bit-identical to the passing rounds.

#define SWZF(x, mask) __int_as_float(__builtin_amdgcn_ds_swizzle(__float_as_int(x), (((mask) << 10) | 0x1F)))
#define SWZI(x, mask) __builtin_amdgcn_ds_swizzle((x), (((mask) << 10) | 0x1F))
// DPP quad_perm: xor1=[1,0,3,2]=0xB1, xor2=[2,3,0,1]=0x4E, xor3=[3,2,1,0]=0x1B.
// Tokens own 8 aligned lanes -> quads never cross tokens.
#define DPPF(x, ctrl) __int_as_float(__builtin_amdgcn_update_dpp(__float_as_int(x), __float_as_int(x), (ctrl), 0xF, 0xF, true))
#define DPPI(x, ctrl) __builtin_amdgcn_update_dpp((x), (x), (ctrl), 0xF, 0xF, true)
#define QP_X1 0xB1
#define QP_X2 0x4E
#define QP_X3 0x1B

__global__ __launch_bounds__(256) void router_topk_kernel(
    const float* __restrict__ logits,
    const float* __restrict__ bias,
    float* __restrict__ out_w,
    float* __restrict__ out_id,
    int T)
{
    const float NEGINF = -__builtin_inff();
    const int tid  = threadIdx.x;
    const int wid  = tid >> 6;                  // wave id within block (0..3)
    const int s    = tid & 7;                   // expert-group owned by this lane
    const int tw   = (tid >> 3) & 7;            // token-in-wave (0..7)
    const int token = blockIdx.x * 32 + (tid >> 3);
    if (token >= T) return;

    // Writeback buffer: 4 waves x 8 tokens x 64 float4 (8KB/wave) = 32KB.
    // Wave-private region -> no barriers; compiler lgkmcnt orders wr->rd.
    __shared__ float4 xp[2048];
    float4* xw = xp + (wid << 9);

    const float* row = logits + (size_t)token * 256 + s * 32;
    const float* brw = bias + s * 32;

    float v[8][4];

    // ---- load my 32 logits (each lane consumes one full 128B cacheline),
    // exact sigmoid (matches np ordering), add bias ----
    #pragma unroll
    for (int c = 0; c < 8; ++c) {
        float4 l = ((const float4*)row)[c];
        float4 b = ((const float4*)brw)[c];
        #pragma unroll
        for (int k = 0; k < 4; ++k) {
            float x = (&l.x)[k];
            v[c][k] = 1.0f / (1.0f + expf(-x)) + (&b.x)[k];
        }
    }

    // ---- group score: sum of top-2 of my 32 biased values (med3 trick) ----
    float t1 = NEGINF, t2 = NEGINF;
    #pragma unroll
    for (int c = 0; c < 8; ++c) {
        #pragma unroll
        for (int k = 0; k < 4; ++k) {
            float val = v[c][k];
            t2 = __builtin_amdgcn_fmed3f(t1, t2, val);
            t1 = fmaxf(t1, val);
        }
    }
    const float gs = t1 + t2;

    // ---- unconditional writeback BEFORE rank: slot = [tw][c][s^tw].
    // Issues overlap the rank/msk compute below; per instr lanes hit 8
    // consecutive float4 (2 lanes/bank) -> conflict-free. ----
    #pragma unroll
    for (int c = 0; c < 8; ++c)
        xw[(tw << 6) | (c << 3) | (s ^ tw)] = make_float4(v[c][0], v[c][1], v[c][2], v[c][3]);

    // ---- rank my group among the 8; keep top-4 ----
    int rank = 0;
    {
        float g1 = DPPF(gs, QP_X1);
        float g2 = DPPF(gs, QP_X2);
        float g3 = DPPF(gs, QP_X3);
        float g4 = SWZF(gs, 4);
        float g5 = DPPF(g4, QP_X1);
        float g6 = DPPF(g4, QP_X2);
        float g7 = DPPF(g4, QP_X3);
        rank += (g1 > gs || (g1 == gs && (s & 1))) ? 1 : 0;
        rank += (g2 > gs || (g2 == gs && (s & 2))) ? 1 : 0;
        rank += (g3 > gs || (g3 == gs && (s & 2))) ? 1 : 0;
        rank += (g4 > gs || (g4 == gs && (s & 4))) ? 1 : 0;
        rank += (g5 > gs || (g5 == gs && (s & 4))) ? 1 : 0;
        rank += (g6 > gs || (g6 == gs && (s & 4))) ? 1 : 0;
        rank += (g7 > gs || (g7 == gs && (s & 4))) ? 1 : 0;
    }
    const bool selected = rank < 4;   // ranks are a permutation -> exactly 4

    // ---- 8-bit selected-group mask, shared by all 8 lanes of the token ----
    int msk = selected ? (1 << s) : 0;
    msk |= DPPI(msk, QP_X1);
    msk |= DPPI(msk, QP_X2);
    msk |= SWZI(msk, 4);

    // ---- my source group = (s>>1)-th set bit of msk (ascending group id) ----
    unsigned m0 = (unsigned)msk;
    int g0 = __builtin_ctz(m0);
    unsigned m1 = m0 & (m0 - 1);
    int g1 = __builtin_ctz(m1);
    unsigned m2 = m1 & (m1 - 1);
    int g2 = __builtin_ctz(m2);
    unsigned m3 = m2 & (m2 - 1);
    int g3 = __builtin_ctz(m3);
    int ga = (s & 2) ? g1 : g0;
    int gb = (s & 2) ? g3 : g2;
    const int grp = (s & 4) ? gb : ga;
    const int h4  = (s & 1) << 2;               // chunk offset within group

    // ---- gather my 4 redistributed chunks (16 values of group grp) ----
    float    f[4][4];
    unsigned pix[4];   // byte k of pix[j] = expert idx of f[j][k]
    {
        const int rb = (tw << 6) | (grp ^ tw);
        #pragma unroll
        for (int j = 0; j < 4; ++j) {
            float4 nb = xw[rb | ((h4 + j) << 3)];
            f[j][0] = nb.x; f[j][1] = nb.y; f[j][2] = nb.z; f[j][3] = nb.w;
        }
        const unsigned ebase = (unsigned)(grp * 32 + (h4 << 2)); // grp*32 + h*16
        const unsigned pbase = ebase * 0x01010101u;
        pix[0] = pbase + 0x03020100u;
        pix[1] = pbase + 0x07060504u;
        pix[2] = pbase + 0x0B0A0908u;
        pix[3] = pbase + 0x0F0E0D0Cu;
    }

    // ---- sort each chunk of 4 descending (ties -> lower idx first).
    // First two CEs: pre-sort idx order is ascending (ia<ib statically),
    // so the tie-break term is compile-time false -> plain value compare. ----
    #pragma unroll
    for (int c = 0; c < 4; ++c) {
        #define CE0(A, B, KM) { \
            unsigned p  = pix[c]; \
            unsigned ia = (p >> (8*(A))) & 0xFFu; \
            unsigned ib = (p >> (8*(B))) & 0xFFu; \
            bool sw = (f[c][A] < f[c][B]); \
            float hv = sw ? f[c][B] : f[c][A]; \
            float lv = sw ? f[c][A] : f[c][B]; \
            f[c][A] = hv; f[c][B] = lv; \
            unsigned ps = (p & (KM)) | (ia << (8*(B))) | (ib << (8*(A))); \
            pix[c] = sw ? ps : p; \
        }
        #define CE(A, B, KM) { \
            unsigned p  = pix[c]; \
            unsigned ia = (p >> (8*(A))) & 0xFFu; \
            unsigned ib = (p >> (8*(B))) & 0xFFu; \
            bool sw = (f[c][A] < f[c][B]) || (f[c][A] == f[c][B] && ia > ib); \
            float hv = sw ? f[c][B] : f[c][A]; \
            float lv = sw ? f[c][A] : f[c][B]; \
            f[c][A] = hv; f[c][B] = lv; \
            unsigned ps = (p & (KM)) | (ia << (8*(B))) | (ib << (8*(A))); \
            pix[c] = sw ? ps : p; \
        }
        CE0(0,1,0xFFFF0000u) CE0(2,3,0x0000FFFFu)
        CE(0,2,0xFF00FF00u) CE(1,3,0x00FF00FFu) CE(1,2,0xFF0000FFu)
        #undef CE
        #undef CE0
    }

    // ---- 8 rounds: global argmax over 32 stream heads, advance winner ----
    float keepV = 0.0f; int keepI = 0;
    #pragma unroll
    for (int r = 0; r < 8; ++r) {
        const int h0 = (int)(pix[0] & 0xFFu);
        const int h1 = (int)(pix[1] & 0xFFu);
        const int h2 = (int)(pix[2] & 0xFFu);
        const int h3 = (int)(pix[3] & 0xFFu);
        float w0v, w1v, bv; int w0i, w1i, bi;
        { bool t = (f[1][0] > f[0][0]); w0v = t ? f[1][0] : f[0][0]; w0i = t ? h1 : h0; }
        { bool t = (f[3][0] > f[2][0]); w1v = t ? f[3][0] : f[2][0]; w1i = t ? h3 : h2; }
        { bool t = (w1v > w0v);         bv  = t ? w1v : w0v;         bi  = t ? w1i : w0i; }
        // 8-lane butterfly argmax; idx tie-break for cross-lane consistency
        { float ov = DPPF(bv, QP_X1); int oi = DPPI(bi, QP_X1);
          bool t = (ov > bv) || (ov == bv && oi < bi); bv = t ? ov : bv; bi = t ? oi : bi; }
        { float ov = DPPF(bv, QP_X2); int oi = DPPI(bi, QP_X2);
          bool t = (ov > bv) || (ov == bv && oi < bi); bv = t ? ov : bv; bi = t ? oi : bi; }
        { float ov = SWZF(bv, 4);     int oi = SWZI(bi, 4);
          bool t = (ov > bv) || (ov == bv && oi < bi); bv = t ? ov : bv; bi = t ? oi : bi; }
        if (s == r) { keepV = bv; keepI = bi; }
        // advance: the unique live chunk whose head idx == bi pops one.
        {
            bool hit = (h0 == bi);
            f[0][0] = hit ? f[0][1] : f[0][0];
            f[0][1] = hit ? f[0][2] : f[0][1];
            f[0][2] = hit ? f[0][3] : f[0][2];
            f[0][3] = hit ? NEGINF  : f[0][3];
            pix[0]  = hit ? (pix[0] >> 8) : pix[0];
        }
        {
            bool hit = (h1 == bi);
            f[1][0] = hit ? f[1][1] : f[1][0];
            f[1][1] = hit ? f[1][2] : f[1][1];
            f[1][2] = hit ? f[1][3] : f[1][2];
            f[1][3] = hit ? NEGINF  : f[1][3];
            pix[1]  = hit ? (pix[1] >> 8) : pix[1];
        }
        {
            bool hit = (h2 == bi);
            f[2][0] = hit ? f[2][1] : f[2][0];
            f[2][1] = hit ? f[2][2] : f[2][1];
            f[2][2] = hit ? f[2][3] : f[2][2];
            f[2][3] = hit ? NEGINF  : f[2][3];
            pix[2]  = hit ? (pix[2] >> 8) : pix[2];
        }
        {
            bool hit = (h3 == bi);
            f[3][0] = hit ? f[3][1] : f[3][0];
            f[3][1] = hit ? f[3][2] : f[3][1];
            f[3][2] = hit ? f[3][3] : f[3][2];
            f[3][3] = hit ? NEGINF  : f[3][3];
            pix[3]  = hit ? (pix[3] >> 8) : pix[3];
        }
    }

    // ---- recover sigmoid score, renormalize, scale, store (coalesced) ----
    float w = keepV - bias[keepI];
    float sum = w;
    sum += DPPF(sum, QP_X1);
    sum += DPPF(sum, QP_X2);
    sum += SWZF(sum, 4);
    w = w / (sum + 1e-20f) * 2.5f;

    const size_t o = (size_t)blockIdx.x * 256 + tid;  // == token*8 + s
    out_w[o]  = w;
    out_id[o] = (float)keepI;
}

extern "C" void kernel_launch(void* const* d_in, const int* in_sizes, int n_in,
                              void* d_out, int out_size, void* d_ws, size_t ws_size,
                              hipStream_t stream) {
    const float* logits = (const float*)d_in[0];
    const float* bias   = (const float*)d_in[1];
    const int E = in_sizes[1];          // 256
    const int T = in_sizes[0] / E;      // 131072
    float* out_w  = (float*)d_out;
    float* out_id = out_w + (size_t)T * 8;
    const int blocks = (T + 31) / 32;
    router_topk_kernel<<<blocks, 256, 0, stream>>>(logits, bias, out_w, out_id, T);
}

// Round 7
// 200.552 us; speedup vs baseline: 1.0215x; 1.0215x over previous
//
#include <hip/hip_runtime.h>
#include <math.h>

// Group-limited MoE router, T=131072 tokens x E=256 experts.
// 8 lanes per token. Round 10 = exact Round-7 structure (best bench, 202.0us:
// coalesced row loads + wave-private LDS transpose, unconditional pre-rank
// compaction writeback, ctz-chain group lookup) plus the one proven-safe trim
// from Round 9: first-layer chunk-sort CEs drop the statically-false idx
// tie-break. Round 9's strided loads are REVERTED: the R7-vs-R9 A/B (same
// LDS/occupancy) showed per-instruction load contiguity is worth ~3us cold
// (strided = 64 cachelines touched/instr, 16B used each; coalesced = 1KB
// contiguous). All compare/tie rules and the exact sigmoid are bit-identical
// to the passing rounds.

#define SWZF(x, mask) __int_as_float(__builtin_amdgcn_ds_swizzle(__float_as_int(x), (((mask) << 10) | 0x1F)))
#define SWZI(x, mask) __builtin_amdgcn_ds_swizzle((x), (((mask) << 10) | 0x1F))
// DPP quad_perm: xor1=[1,0,3,2]=0xB1, xor2=[2,3,0,1]=0x4E, xor3=[3,2,1,0]=0x1B.
// Tokens own 8 aligned lanes -> quads never cross tokens.
#define DPPF(x, ctrl) __int_as_float(__builtin_amdgcn_update_dpp(__float_as_int(x), __float_as_int(x), (ctrl), 0xF, 0xF, true))
#define DPPI(x, ctrl) __builtin_amdgcn_update_dpp((x), (x), (ctrl), 0xF, 0xF, true)
#define QP_X1 0xB1
#define QP_X2 0x4E
#define QP_X3 0x1B

__global__ __launch_bounds__(256) void router_topk_kernel(
    const float* __restrict__ logits,
    const float* __restrict__ bias,
    float* __restrict__ out_w,
    float* __restrict__ out_id,
    int T)
{
    const float NEGINF = -__builtin_inff();
    const int tid  = threadIdx.x;
    const int lane = tid & 63;
    const int wid  = tid >> 6;                  // wave id within block (0..3)
    const int s    = tid & 7;                   // expert-group owned by this lane
    const int tw   = (tid >> 3) & 7;            // token-in-wave (0..7)
    const int token = blockIdx.x * 32 + (tid >> 3);
    const int wtok0 = blockIdx.x * 32 + (wid << 3);

    // 4 waves x 512 float4 slots (8KB/wave) = 32KB; reused twice:
    // phase 1: raw logits staging (coalesced load + xor transpose)
    // phase 2: biased values in [tw][chunk][s^tw] layout for compaction
    __shared__ float4 xp[2048];
    float4* xw = xp + (wid << 9);

    // ---- coalesced load: instruction j covers token (wtok0+j)'s full 1KB row
    {
        float4 gbuf[8];
        #pragma unroll
        for (int j = 0; j < 8; ++j) {
            int r = wtok0 + j;
            r = (r < T) ? r : (T - 1);
            gbuf[j] = ((const float4*)(logits + ((size_t)r << 8)))[lane];
        }
        #pragma unroll
        for (int j = 0; j < 8; ++j)
            xw[(j << 6) | (lane ^ j)] = gbuf[j];
        // wave-local buffer; lockstep + compiler lgkmcnt orders write->read.
    }

    const float* brw = bias + s * 32;
    float v[8][4];

    // ---- fetch my 32 experts, exact sigmoid, add bias ----
    #pragma unroll
    for (int c = 0; c < 8; ++c) {
        float4 l = xw[(tw << 6) | (s << 3) | (c ^ tw)];
        float4 b = ((const float4*)brw)[c];
        #pragma unroll
        for (int k = 0; k < 4; ++k) {
            float x = (&l.x)[k];
            v[c][k] = 1.0f / (1.0f + expf(-x)) + (&b.x)[k];
        }
    }

    // ---- group score: sum of top-2 of my 32 biased values (med3 trick) ----
    float t1 = NEGINF, t2 = NEGINF;
    #pragma unroll
    for (int c = 0; c < 8; ++c) {
        #pragma unroll
        for (int k = 0; k < 4; ++k) {
            float val = v[c][k];
            t2 = __builtin_amdgcn_fmed3f(t1, t2, val);
            t1 = fmaxf(t1, val);
        }
    }
    const float gs = t1 + t2;

    // ---- unconditional writeback BEFORE rank: slot = [tw][c][s^tw].
    // Issues overlap the rank/msk compute below; per instr lanes hit 8
    // consecutive float4 (2 lanes/bank) -> conflict-free. ----
    #pragma unroll
    for (int c = 0; c < 8; ++c)
        xw[(tw << 6) | (c << 3) | (s ^ tw)] = make_float4(v[c][0], v[c][1], v[c][2], v[c][3]);

    // ---- rank my group among the 8; keep top-4 ----
    int rank = 0;
    {
        float g1 = DPPF(gs, QP_X1);
        float g2 = DPPF(gs, QP_X2);
        float g3 = DPPF(gs, QP_X3);
        float g4 = SWZF(gs, 4);
        float g5 = DPPF(g4, QP_X1);
        float g6 = DPPF(g4, QP_X2);
        float g7 = DPPF(g4, QP_X3);
        rank += (g1 > gs || (g1 == gs && (s & 1))) ? 1 : 0;
        rank += (g2 > gs || (g2 == gs && (s & 2))) ? 1 : 0;
        rank += (g3 > gs || (g3 == gs && (s & 2))) ? 1 : 0;
        rank += (g4 > gs || (g4 == gs && (s & 4))) ? 1 : 0;
        rank += (g5 > gs || (g5 == gs && (s & 4))) ? 1 : 0;
        rank += (g6 > gs || (g6 == gs && (s & 4))) ? 1 : 0;
        rank += (g7 > gs || (g7 == gs && (s & 4))) ? 1 : 0;
    }
    const bool selected = rank < 4;   // ranks are a permutation -> exactly 4

    // ---- 8-bit selected-group mask, shared by all 8 lanes of the token ----
    int msk = selected ? (1 << s) : 0;
    msk |= DPPI(msk, QP_X1);
    msk |= DPPI(msk, QP_X2);
    msk |= SWZI(msk, 4);

    // ---- my source group = (s>>1)-th set bit of msk (ascending group id) ----
    unsigned m0 = (unsigned)msk;
    int g0 = __builtin_ctz(m0);
    unsigned m1 = m0 & (m0 - 1);
    int g1 = __builtin_ctz(m1);
    unsigned m2 = m1 & (m1 - 1);
    int g2 = __builtin_ctz(m2);
    unsigned m3 = m2 & (m2 - 1);
    int g3 = __builtin_ctz(m3);
    int ga = (s & 2) ? g1 : g0;
    int gb = (s & 2) ? g3 : g2;
    const int grp = (s & 4) ? gb : ga;
    const int h4  = (s & 1) << 2;               // chunk offset within group

    // ---- gather my 4 redistributed chunks (16 values of group grp) ----
    float    f[4][4];
    unsigned pix[4];   // byte k of pix[j] = expert idx of f[j][k]
    {
        const int rb = (tw << 6) | (grp ^ tw);
        #pragma unroll
        for (int j = 0; j < 4; ++j) {
            float4 nb = xw[rb | ((h4 + j) << 3)];
            f[j][0] = nb.x; f[j][1] = nb.y; f[j][2] = nb.z; f[j][3] = nb.w;
        }
        const unsigned ebase = (unsigned)(grp * 32 + (h4 << 2)); // grp*32 + h*16
        const unsigned pbase = ebase * 0x01010101u;
        pix[0] = pbase + 0x03020100u;
        pix[1] = pbase + 0x07060504u;
        pix[2] = pbase + 0x0B0A0908u;
        pix[3] = pbase + 0x0F0E0D0Cu;
    }

    // ---- sort each chunk of 4 descending (ties -> lower idx first).
    // First two CEs: pre-sort idx order is ascending (ia<ib statically),
    // so the tie-break term is compile-time false -> plain value compare. ----
    #pragma unroll
    for (int c = 0; c < 4; ++c) {
        #define CE0(A, B, KM) { \
            unsigned p  = pix[c]; \
            unsigned ia = (p >> (8*(A))) & 0xFFu; \
            unsigned ib = (p >> (8*(B))) & 0xFFu; \
            bool sw = (f[c][A] < f[c][B]); \
            float hv = sw ? f[c][B] : f[c][A]; \
            float lv = sw ? f[c][A] : f[c][B]; \
            f[c][A] = hv; f[c][B] = lv; \
            unsigned ps = (p & (KM)) | (ia << (8*(B))) | (ib << (8*(A))); \
            pix[c] = sw ? ps : p; \
        }
        #define CE(A, B, KM) { \
            unsigned p  = pix[c]; \
            unsigned ia = (p >> (8*(A))) & 0xFFu; \
            unsigned ib = (p >> (8*(B))) & 0xFFu; \
            bool sw = (f[c][A] < f[c][B]) || (f[c][A] == f[c][B] && ia > ib); \
            float hv = sw ? f[c][B] : f[c][A]; \
            float lv = sw ? f[c][A] : f[c][B]; \
            f[c][A] = hv; f[c][B] = lv; \
            unsigned ps = (p & (KM)) | (ia << (8*(B))) | (ib << (8*(A))); \
            pix[c] = sw ? ps : p; \
        }
        CE0(0,1,0xFFFF0000u) CE0(2,3,0x0000FFFFu)
        CE(0,2,0xFF00FF00u) CE(1,3,0x00FF00FFu) CE(1,2,0xFF0000FFu)
        #undef CE
        #undef CE0
    }

    // ---- 8 rounds: global argmax over 32 stream heads, advance winner ----
    // All lanes hold live selected data. Strict > keeps left (lower chunk =
    // lower expert idx) on ties; idx ascends across lanes and chunks.
    float keepV = 0.0f; int keepI = 0;
    #pragma unroll
    for (int r = 0; r < 8; ++r) {
        const int h0 = (int)(pix[0] & 0xFFu);
        const int h1 = (int)(pix[1] & 0xFFu);
        const int h2 = (int)(pix[2] & 0xFFu);
        const int h3 = (int)(pix[3] & 0xFFu);
        float w0v, w1v, bv; int w0i, w1i, bi;
        { bool t = (f[1][0] > f[0][0]); w0v = t ? f[1][0] : f[0][0]; w0i = t ? h1 : h0; }
        { bool t = (f[3][0] > f[2][0]); w1v = t ? f[3][0] : f[2][0]; w1i = t ? h3 : h2; }
        { bool t = (w1v > w0v);         bv  = t ? w1v : w0v;         bi  = t ? w1i : w0i; }
        // 8-lane butterfly argmax; idx tie-break for cross-lane consistency
        { float ov = DPPF(bv, QP_X1); int oi = DPPI(bi, QP_X1);
          bool t = (ov > bv) || (ov == bv && oi < bi); bv = t ? ov : bv; bi = t ? oi : bi; }
        { float ov = DPPF(bv, QP_X2); int oi = DPPI(bi, QP_X2);
          bool t = (ov > bv) || (ov == bv && oi < bi); bv = t ? ov : bv; bi = t ? oi : bi; }
        { float ov = SWZF(bv, 4);     int oi = SWZI(bi, 4);
          bool t = (ov > bv) || (ov == bv && oi < bi); bv = t ? ov : bv; bi = t ? oi : bi; }
        if (s == r) { keepV = bv; keepI = bi; }
        // advance: the unique live chunk whose head idx == bi pops one.
        // (Exhausted chunks have head byte 0; a false hit only shifts NEGINFs.)
        {
            bool hit = (h0 == bi);
            f[0][0] = hit ? f[0][1] : f[0][0];
            f[0][1] = hit ? f[0][2] : f[0][1];
            f[0][2] = hit ? f[0][3] : f[0][2];
            f[0][3] = hit ? NEGINF  : f[0][3];
            pix[0]  = hit ? (pix[0] >> 8) : pix[0];
        }
        {
            bool hit = (h1 == bi);
            f[1][0] = hit ? f[1][1] : f[1][0];
            f[1][1] = hit ? f[1][2] : f[1][1];
            f[1][2] = hit ? f[1][3] : f[1][2];
            f[1][3] = hit ? NEGINF  : f[1][3];
            pix[1]  = hit ? (pix[1] >> 8) : pix[1];
        }
        {
            bool hit = (h2 == bi);
            f[2][0] = hit ? f[2][1] : f[2][0];
            f[2][1] = hit ? f[2][2] : f[2][1];
            f[2][2] = hit ? f[2][3] : f[2][2];
            f[2][3] = hit ? NEGINF  : f[2][3];
            pix[2]  = hit ? (pix[2] >> 8) : pix[2];
        }
        {
            bool hit = (h3 == bi);
            f[3][0] = hit ? f[3][1] : f[3][0];
            f[3][1] = hit ? f[3][2] : f[3][1];
            f[3][2] = hit ? f[3][3] : f[3][2];
            f[3][3] = hit ? NEGINF  : f[3][3];
            pix[3]  = hit ? (pix[3] >> 8) : pix[3];
        }
    }

    // ---- recover sigmoid score, renormalize, scale, store (coalesced) ----
    float w = keepV - bias[keepI];
    float sum = w;
    sum += DPPF(sum, QP_X1);
    sum += DPPF(sum, QP_X2);
    sum += SWZF(sum, 4);
    w = w / (sum + 1e-20f) * 2.5f;

    if (token < T) {
        const size_t o = (size_t)blockIdx.x * 256 + tid;  // == token*8 + s
        out_w[o]  = w;
        out_id[o] = (float)keepI;
    }
}

extern "C" void kernel_launch(void* const* d_in, const int* in_sizes, int n_in,
                              void* d_out, int out_size, void* d_ws, size_t ws_size,
                              hipStream_t stream) {
    const float* logits = (const float*)d_in[0];
    const float* bias   = (const float*)d_in[1];
    const int E = in_sizes[1];          // 256
    const int T = in_sizes[0] / E;      // 131072
    float* out_w  = (float*)d_out;
    float* out_id = out_w + (size_t)T * 8;
    const int blocks = (T + 31) / 32;
    router_topk_kernel<<<blocks, 256, 0, stream>>>(logits, bias, out_w, out_id, T);
}